// Round 10
// baseline (285.107 us; speedup 1.0000x reference)
//
#include <hip/hip_runtime.h>
#include <hip/hip_bf16.h>

// TransitionGNN fused pipeline, r10.
// Single change vs r9 (clean A/B): edge kernel rebuilt as 2-pass half-K:
//   build A(256 k-cols) -> barrier -> 8-kt BARRIER-FREE mfma run -> barrier
//   -> build -> barrier -> run.  16 barriers -> 3; B-frag L2 loads pipeline
//   across kts inside each run (the 16-barrier loop drained vmcnt every kt,
//   which is why edge sat at 119us = 4x its 29us MFMA floor for 4 rounds).
// mega_prep / combo / node_fused byte-identical to r9.

using bf16 = __hip_bfloat16;
typedef __attribute__((ext_vector_type(8))) short bf16x8;
typedef __attribute__((ext_vector_type(4))) short short4v;
typedef __attribute__((ext_vector_type(4))) float f32x4;

#define LDK 40   // LDS row stride (32 + 8 pad) for GEMM staging tiles
#define LDA 264  // edge A-tile row stride (256 + 8 pad; 2-way bank alias only)
#define LDN 520  // 512-col activation tile stride

__device__ __forceinline__ short f2bf(float f) {
  bf16 h = __float2bfloat16(f);
  return *reinterpret_cast<short*>(&h);
}
__device__ __forceinline__ float bs2f(short s) {
  bf16 h = *reinterpret_cast<bf16*>(&s);
  return __bfloat162float(h);
}
__device__ __forceinline__ f32x4 mfma16(bf16x8 a, bf16x8 b, f32x4 c) {
  return __builtin_amdgcn_mfma_f32_16x16x32_bf16(a, b, c, 0, 0, 0);
}
// load 8 consecutive fp32 -> bf16x8 (32B-aligned source)
__device__ __forceinline__ bf16x8 ld8f(const float* p) {
  float4 a = *(const float4*)p;
  float4 b = *(const float4*)(p + 4);
  bf16x8 o;
  o[0] = f2bf(a.x); o[1] = f2bf(a.y); o[2] = f2bf(a.z); o[3] = f2bf(a.w);
  o[4] = f2bf(b.x); o[5] = f2bf(b.y); o[6] = f2bf(b.z); o[7] = f2bf(b.w);
  return o;
}

// ---------------------------------------------------------------- mega_prep
// z=0: eW3 fp32 -> eW3b bf16; z=1: nW1_agg transpose -> nW1at; z=2..7: frag.
__global__ __launch_bounds__(256) void mega_prep(
    const float* __restrict__ eW3, short* __restrict__ eW3b,
    const float* __restrict__ nW1, unsigned short* __restrict__ nW1at,
    const float* __restrict__ eW1, short* __restrict__ eW1f,
    const float* __restrict__ eW2, short* __restrict__ eW2f,
    short* __restrict__ nW1nf, const float* __restrict__ nW2,
    short* __restrict__ nW2f, const float* __restrict__ nW3,
    short* __restrict__ nW3f) {
  __shared__ unsigned short tile[32][33];
  const int z = blockIdx.z, bx = blockIdx.x, t = threadIdx.x;
  if (z == 0) {
    if (bx >= 256) return;
    int i = (bx * 256 + t) * 4;
    float4 v = *(const float4*)(eW3 + i);
    short4v o;
    o.x = f2bf(v.x); o.y = f2bf(v.y); o.z = f2bf(v.z); o.w = f2bf(v.w);
    *(short4v*)(eW3b + i) = o;
    return;
  }
  if (z == 1) {
    if (bx >= 256) return;
    const float* src = nW1 + 132 * 512;
    int bc = (bx & 15) * 32, br = (bx >> 4) * 32;
    int tx = t & 31, ty = t >> 5;
    for (int i = ty; i < 32; i += 8) {
      short s = f2bf(src[(size_t)(br + i) * 512 + bc + tx]);
      tile[i][tx] = *reinterpret_cast<unsigned short*>(&s);
    }
    __syncthreads();
    for (int i = ty; i < 32; i += 8)
      nW1at[(size_t)(bc + i) * 512 + br + tx] = tile[tx][i];
    return;
  }
  const float* W;
  short* out;
  int src_sh, ldw, goff, tot_sh, total;
  switch (z) {
    case 2: W = eW1;            out = eW1f;  src_sh = 5; ldw = 512; goff = 0;  tot_sh = 6; total = 65536;  break;
    case 3: W = eW1 + 128*512;  out = eW1f;  src_sh = 5; ldw = 512; goff = 32; tot_sh = 6; total = 65536;  break;
    case 4: W = eW2;            out = eW2f;  src_sh = 5; ldw = 512; goff = 0;  tot_sh = 5; total = 262144; break;
    case 5: W = nW1;            out = nW1nf; src_sh = 5; ldw = 512; goff = 0;  tot_sh = 5; total = 65536;  break;
    case 6: W = nW2;            out = nW2f;  src_sh = 5; ldw = 512; goff = 0;  tot_sh = 5; total = 262144; break;
    default: W = nW3;           out = nW3f;  src_sh = 3; ldw = 128; goff = 0;  tot_sh = 3; total = 65536;  break;
  }
  int o = bx * 256 + t;
  if (o >= total) return;
  int j = o & 7, lane = (o >> 3) & 63, blk = o >> 9;
  int kt = blk >> src_sh, gg = blk & ((1 << src_sh) - 1);
  int q = lane >> 4, lc = lane & 15;
  out[(((size_t)(kt << tot_sh) + gg + goff) << 9) + (o & 511)] =
      f2bf(W[(size_t)(kt * 32 + q * 8 + j) * ldw + gg * 16 + lc]);
}

// ---------------------------------------------------------------- combo
// blocks 0..63: Wc frag tiles; 64..95: bias fold (32-way); 96..607: PQ gemm.
__global__ __launch_bounds__(256) void combo(
    const bf16* __restrict__ nW1at, const bf16* __restrict__ eW3b,
    short* __restrict__ Wcf, const float* __restrict__ eb3,
    const float* __restrict__ nb1, const float* __restrict__ nW1,
    float* __restrict__ bfold, const float* __restrict__ states,
    const bf16* __restrict__ eW1f, const float* __restrict__ eb1,
    bf16* __restrict__ PQ) {
  __shared__ short Al[64 * LDK];
  __shared__ short Bl[64 * LDK];
  __shared__ float red[256];
  const int bid = blockIdx.x;
  const int t = threadIdx.x;
  const int wid = t >> 6, lane = t & 63, q = lane >> 4, lc = lane & 15;
  const f32x4 zz = {0.f, 0.f, 0.f, 0.f};

  if (bid < 64) {
    const int wm = wid >> 1, wn = wid & 1;
    const int n0 = (bid >> 3) * 64, k0 = (bid & 7) * 64;
    f32x4 acc[2][2];
#pragma unroll
    for (int mb = 0; mb < 2; ++mb)
#pragma unroll
      for (int nb = 0; nb < 2; ++nb) acc[mb][nb] = zz;
    const int sr = t >> 2, seg = t & 3;
    for (int h0 = 0; h0 < 512; h0 += 32) {
      *(uint4*)&Al[sr * LDK + seg * 8] =
          *(const uint4*)(nW1at + (size_t)(n0 + sr) * 512 + h0 + seg * 8);
      *(uint4*)&Bl[sr * LDK + seg * 8] =
          *(const uint4*)(eW3b + (size_t)(k0 + sr) * 512 + h0 + seg * 8);
      __syncthreads();
      bf16x8 af[2], bfr[2];
#pragma unroll
      for (int mb = 0; mb < 2; ++mb)
        af[mb] = *(const bf16x8*)&Al[(wm * 32 + mb * 16 + lc) * LDK + q * 8];
#pragma unroll
      for (int nb = 0; nb < 2; ++nb)
        bfr[nb] = *(const bf16x8*)&Bl[(wn * 32 + nb * 16 + lc) * LDK + q * 8];
#pragma unroll
      for (int mb = 0; mb < 2; ++mb)
#pragma unroll
        for (int nb = 0; nb < 2; ++nb)
          acc[mb][nb] = mfma16(af[mb], bfr[nb], acc[mb][nb]);
      __syncthreads();
    }
#pragma unroll
    for (int mb = 0; mb < 2; ++mb)
#pragma unroll
      for (int nb = 0; nb < 2; ++nb)
#pragma unroll
        for (int r = 0; r < 4; ++r) {
          int n = n0 + wm * 32 + mb * 16 + q * 4 + r;
          int k = k0 + wn * 32 + nb * 16 + lc;
          int kt = k >> 5, kin = k & 31, qf = kin >> 3, jf = kin & 7;
          Wcf[(((size_t)kt * 32 + (n >> 4)) * 64 + qf * 16 + (n & 15)) * 8 +
              jf] = f2bf(acc[mb][nb][r]);
        }
    return;
  }
  if (bid < 96) {
    const int n = (bid - 64) * 16 + (t & 15);
    const int sl = t >> 4;
    float s = 0.f;
#pragma unroll 8
    for (int h = sl * 32; h < sl * 32 + 32; ++h)
      s += eb3[h] * nW1[(size_t)(132 + h) * 512 + n];
    red[sl * 16 + (t & 15)] = s;
    __syncthreads();
    if (t < 16) {
      float tot = 0.f;
#pragma unroll
      for (int k = 0; k < 16; ++k) tot += red[k * 16 + t];
      bfold[(bid - 64) * 16 + t] = nb1[(bid - 64) * 16 + t] + 15.f * tot;
    }
    return;
  }
  const int m0 = (bid - 96) * 16;
  f32x4 acc[16];
#pragma unroll
  for (int nb = 0; nb < 16; ++nb) acc[nb] = zz;
#pragma unroll
  for (int kt = 0; kt < 4; ++kt) {
    bf16x8 af = ld8f(states + (size_t)(m0 + lc) * 128 + kt * 32 + q * 8);
#pragma unroll
    for (int nb = 0; nb < 16; ++nb) {
      bf16x8 bfr = *(const bf16x8*)(eW1f +
                                    (((size_t)kt * 64 + wid * 16 + nb) * 64 +
                                     lane) * 8);
      acc[nb] = mfma16(af, bfr, acc[nb]);
    }
  }
#pragma unroll
  for (int nb = 0; nb < 16; ++nb) {
    int col = wid * 256 + nb * 16 + lc;
    float bv = (col < 512) ? eb1[col] : 0.f;
#pragma unroll
    for (int r = 0; r < 4; ++r)
      PQ[(size_t)(m0 + q * 4 + r) * 1024 + col] =
          __float2bfloat16(acc[nb][r] + bv);
  }
}

// ---------------------------------------------------------------- edge v5
// 2-pass half-K: build A(256 cols) -> barrier -> 8-kt barrier-free MFMA run.
// 3 barriers total (was 16). B-frags direct global from eW2f; A-tile 34 KB.
__global__ __launch_bounds__(512, 4) void edge_ln_seg5(
    const bf16* __restrict__ PQ, const bf16* __restrict__ Wf,
    const float* __restrict__ b2, const float* __restrict__ g,
    const float* __restrict__ be, bf16* __restrict__ S) {
  __shared__ short At[64 * LDA];
  __shared__ float s_sum[64 * 8];
  __shared__ float s_sq[64 * 8];
  const int t = threadIdx.x;
  const int w = t >> 6, lane = t & 63, q = lane >> 4, lc = lane & 15;
  const int g0 = blockIdx.x * 4;
  const int bb = g0 >> 4;
  const f32x4 zz = {0.f, 0.f, 0.f, 0.f};
  f32x4 acc[4][4];
#pragma unroll
  for (int mb = 0; mb < 4; ++mb)
#pragma unroll
    for (int nb = 0; nb < 4; ++nb) acc[mb][nb] = zz;

  // A-build mapping: thread t -> row ar (0..63), 4 k's at kk (within 32-col kt)
  const int ar = t >> 3;
  const int kk = (t & 7) * 4;
  const int gA = ar >> 4;
  const int slot = ar & 15;
  const int aiA = (g0 & 15) + gA;
  const bool padA = (slot == 15);
  const int dstA = padA ? 0 : slot + (slot >= aiA ? 1 : 0);
  const bf16* pA = PQ + (size_t)(g0 + gA) * 1024 + kk;
  const bf16* qA = PQ + (size_t)(bb * 16 + dstA) * 1024 + 512 + kk;

#pragma unroll 1
  for (int p = 0; p < 2; ++p) {
    if (p) __syncthreads();  // prior-pass A reads complete before rebuild
    // build 8 kts (16 PQ loads issued as one batch; pipelined under vmcnt)
    if (!padA) {
#pragma unroll
      for (int kb = 0; kb < 8; ++kb) {
        int kt = p * 8 + kb;
        short4v pv = *(const short4v*)(pA + kt * 32);
        short4v qv = *(const short4v*)(qA + kt * 32);
        short4v av;
        av.x = f2bf(fmaxf(bs2f(pv.x) + bs2f(qv.x), 0.f));
        av.y = f2bf(fmaxf(bs2f(pv.y) + bs2f(qv.y), 0.f));
        av.z = f2bf(fmaxf(bs2f(pv.z) + bs2f(qv.z), 0.f));
        av.w = f2bf(fmaxf(bs2f(pv.w) + bs2f(qv.w), 0.f));
        *(short4v*)&At[ar * LDA + kb * 32 + kk] = av;
      }
    } else {
      const short4v zv = {0, 0, 0, 0};
#pragma unroll
      for (int kb = 0; kb < 8; ++kb)
        *(short4v*)&At[ar * LDA + kb * 32 + kk] = zv;
    }
    __syncthreads();
    // 8-kt barrier-free MFMA run: B loads pipeline across kts
#pragma unroll 2
    for (int kb = 0; kb < 8; ++kb) {
      int kt = p * 8 + kb;
      bf16x8 bfr[4], af[4];
#pragma unroll
      for (int nb = 0; nb < 4; ++nb)
        bfr[nb] = *(const bf16x8*)(Wf +
                                   (((size_t)kt * 32 + w * 4 + nb) * 64 + lane) *
                                       8);
#pragma unroll
      for (int mb = 0; mb < 4; ++mb)
        af[mb] = *(const bf16x8*)&At[(mb * 16 + lc) * LDA + kb * 32 + q * 8];
#pragma unroll
      for (int mb = 0; mb < 4; ++mb)
#pragma unroll
        for (int nb = 0; nb < 4; ++nb)
          acc[mb][nb] = mfma16(af[mb], bfr[nb], acc[mb][nb]);
    }
  }

  // epilogue: +eb2, LN over 512 cols, relu, masked 15-row segment-sum
  float bv[4], gv[4], bev[4];
#pragma unroll
  for (int nb = 0; nb < 4; ++nb) {
    int col = w * 64 + nb * 16 + lc;
    bv[nb] = b2[col];
    gv[nb] = g[col];
    bev[nb] = be[col];
  }
#pragma unroll
  for (int mb = 0; mb < 4; ++mb)
#pragma unroll
    for (int nb = 0; nb < 4; ++nb)
#pragma unroll
      for (int r = 0; r < 4; ++r) acc[mb][nb][r] += bv[nb];

#pragma unroll
  for (int mb = 0; mb < 4; ++mb) {
    float ps[4] = {0, 0, 0, 0}, pq2[4] = {0, 0, 0, 0};
#pragma unroll
    for (int nb = 0; nb < 4; ++nb)
#pragma unroll
      for (int r = 0; r < 4; ++r) {
        float x = acc[mb][nb][r];
        ps[r] += x;
        pq2[r] += x * x;
      }
#pragma unroll
    for (int d = 1; d < 16; d <<= 1)
#pragma unroll
      for (int r = 0; r < 4; ++r) {
        ps[r] += __shfl_xor(ps[r], d, 64);
        pq2[r] += __shfl_xor(pq2[r], d, 64);
      }
    if (lc == 0)
#pragma unroll
      for (int r = 0; r < 4; ++r) {
        int row = mb * 16 + q * 4 + r;
        s_sum[row * 8 + w] = ps[r];
        s_sq[row * 8 + w] = pq2[r];
      }
  }
  __syncthreads();
#pragma unroll
  for (int mb = 0; mb < 4; ++mb) {
    float sv[4] = {0, 0, 0, 0};
#pragma unroll
    for (int r = 0; r < 4; ++r) {
      int row = mb * 16 + q * 4 + r;
      float tot = 0.f, tsq = 0.f;
#pragma unroll
      for (int wv = 0; wv < 8; ++wv) {
        tot += s_sum[row * 8 + wv];
        tsq += s_sq[row * 8 + wv];
      }
      float m = tot * (1.f / 512.f);
      float rstd = rsqrtf(tsq * (1.f / 512.f) - m * m + 1e-5f);
#pragma unroll
      for (int nb = 0; nb < 4; ++nb) {
        float h = (acc[mb][nb][r] - m) * rstd * gv[nb] + bev[nb];
        h = fmaxf(h, 0.f);
        if (q * 4 + r != 15) sv[nb] += h;
      }
    }
#pragma unroll
    for (int nb = 0; nb < 4; ++nb) {
      sv[nb] += __shfl_xor(sv[nb], 16, 64);
      sv[nb] += __shfl_xor(sv[nb], 32, 64);
    }
    if (lane < 16)
#pragma unroll
      for (int nb = 0; nb < 4; ++nb)
        S[(size_t)(g0 + mb) * 512 + w * 64 + nb * 16 + lc] =
            __float2bfloat16(sv[nb]);
  }
}

// ---------------------------------------------------------------- node_fused
__global__ __launch_bounds__(256) void node_fused(
    const float* __restrict__ states, const bf16* __restrict__ S,
    const bf16* __restrict__ nW1nf, const bf16* __restrict__ Wcf,
    const bf16* __restrict__ nW2f, const bf16* __restrict__ nW3f,
    const float* __restrict__ bfold, const int* __restrict__ action,
    const float* __restrict__ nW1, const float* __restrict__ nb2,
    const float* __restrict__ ng, const float* __restrict__ nbt,
    const float* __restrict__ nb3, float* __restrict__ Out) {
  __shared__ short n1s[16 * LDN];
  __shared__ float s_sum[16 * 4];
  __shared__ float s_sq[16 * 4];
  const int t = threadIdx.x;
  const int wid = t >> 6, lane = t & 63, q = lane >> 4, lc = lane & 15;
  const int m0 = blockIdx.x * 16;
  const f32x4 zz = {0.f, 0.f, 0.f, 0.f};

  f32x4 acc[8];
#pragma unroll
  for (int nb = 0; nb < 8; ++nb) acc[nb] = zz;
#pragma unroll
  for (int kt = 0; kt < 4; ++kt) {
    bf16x8 af = ld8f(states + (size_t)(m0 + lc) * 128 + kt * 32 + q * 8);
#pragma unroll
    for (int nb = 0; nb < 8; ++nb) {
      bf16x8 bfr = *(const bf16x8*)(nW1nf +
                                    (((size_t)kt * 32 + wid * 8 + nb) * 64 +
                                     lane) * 8);
      acc[nb] = mfma16(af, bfr, acc[nb]);
    }
  }
#pragma unroll 2
  for (int kt = 0; kt < 16; ++kt) {
    bf16x8 af = *(const bf16x8*)(S + (size_t)(m0 + lc) * 512 + kt * 32 + q * 8);
#pragma unroll
    for (int nb = 0; nb < 8; ++nb) {
      bf16x8 bfr = *(const bf16x8*)(Wcf +
                                    (((size_t)kt * 32 + wid * 8 + nb) * 64 +
                                     lane) * 8);
      acc[nb] = mfma16(af, bfr, acc[nb]);
    }
  }
  {
    int a = action[m0 >> 4];
    int aw = a >> 2, ac4 = a & 3;
#pragma unroll
    for (int nb = 0; nb < 8; ++nb) {
      int col = wid * 128 + nb * 16 + lc;
      float bv = bfold[col];
      float awv = nW1[(size_t)(128 + ac4) * 512 + col];
#pragma unroll
      for (int r = 0; r < 4; ++r) {
        int row = q * 4 + r;
        float x = acc[nb][r] + bv + (row == aw ? awv : 0.f);
        n1s[row * LDN + col] = f2bf(fmaxf(x, 0.f));
      }
    }
  }
  __syncthreads();

  f32x4 acc2[8];
#pragma unroll
  for (int nb = 0; nb < 8; ++nb) acc2[nb] = zz;
#pragma unroll 2
  for (int kt = 0; kt < 16; ++kt) {
    bf16x8 af = *(const bf16x8*)&n1s[lc * LDN + kt * 32 + q * 8];
#pragma unroll
    for (int nb = 0; nb < 8; ++nb) {
      bf16x8 bfr = *(const bf16x8*)(nW2f +
                                    (((size_t)kt * 32 + wid * 8 + nb) * 64 +
                                     lane) * 8);
      acc2[nb] = mfma16(af, bfr, acc2[nb]);
    }
  }
  float gv[8], bev[8];
  {
    float ps[4] = {0, 0, 0, 0}, pq2[4] = {0, 0, 0, 0};
#pragma unroll
    for (int nb = 0; nb < 8; ++nb) {
      int col = wid * 128 + nb * 16 + lc;
      float bv = nb2[col];
      gv[nb] = ng[col];
      bev[nb] = nbt[col];
#pragma unroll
      for (int r = 0; r < 4; ++r) {
        acc2[nb][r] += bv;
        ps[r] += acc2[nb][r];
        pq2[r] += acc2[nb][r] * acc2[nb][r];
      }
    }
#pragma unroll
    for (int d = 1; d < 16; d <<= 1)
#pragma unroll
      for (int r = 0; r < 4; ++r) {
        ps[r] += __shfl_xor(ps[r], d, 64);
        pq2[r] += __shfl_xor(pq2[r], d, 64);
      }
    if (lc == 0)
#pragma unroll
      for (int r = 0; r < 4; ++r) {
        s_sum[(q * 4 + r) * 4 + wid] = ps[r];
        s_sq[(q * 4 + r) * 4 + wid] = pq2[r];
      }
  }
  __syncthreads();
#pragma unroll
  for (int r = 0; r < 4; ++r) {
    int row = q * 4 + r;
    float tot = 0.f, tsq = 0.f;
#pragma unroll
    for (int wv = 0; wv < 4; ++wv) {
      tot += s_sum[row * 4 + wv];
      tsq += s_sq[row * 4 + wv];
    }
    float m = tot * (1.f / 512.f);
    float rstd = rsqrtf(tsq * (1.f / 512.f) - m * m + 1e-5f);
#pragma unroll
    for (int nb = 0; nb < 8; ++nb) {
      int col = wid * 128 + nb * 16 + lc;
      float h = (acc2[nb][r] - m) * rstd * gv[nb] + bev[nb];
      n1s[row * LDN + col] = f2bf(fmaxf(h, 0.f));
    }
  }
  __syncthreads();

  f32x4 acc3[2];
#pragma unroll
  for (int nb = 0; nb < 2; ++nb) acc3[nb] = zz;
#pragma unroll 2
  for (int kt = 0; kt < 16; ++kt) {
    bf16x8 af = *(const bf16x8*)&n1s[lc * LDN + kt * 32 + q * 8];
#pragma unroll
    for (int nb = 0; nb < 2; ++nb) {
      bf16x8 bfr = *(const bf16x8*)(nW3f +
                                    (((size_t)kt * 8 + wid * 2 + nb) * 64 +
                                     lane) * 8);
      acc3[nb] = mfma16(af, bfr, acc3[nb]);
    }
  }
#pragma unroll
  for (int nb = 0; nb < 2; ++nb) {
    int col = wid * 32 + nb * 16 + lc;
    float b3 = nb3[col];
#pragma unroll
    for (int r = 0; r < 4; ++r)
      Out[(size_t)(m0 + q * 4 + r) * 128 + col] = acc3[nb][r] + b3;
  }
}

// ---------------------------------------------------------------- launch
extern "C" void kernel_launch(void* const* d_in, const int* in_sizes, int n_in,
                              void* d_out, int out_size, void* d_ws,
                              size_t ws_size, hipStream_t stream) {
  const float* states = (const float*)d_in[0];
  const int* action = (const int*)d_in[1];
  const float* eW1 = (const float*)d_in[2];
  const float* eb1 = (const float*)d_in[3];
  const float* eW2 = (const float*)d_in[4];
  const float* eb2 = (const float*)d_in[5];
  const float* eg = (const float*)d_in[6];
  const float* ebt = (const float*)d_in[7];
  const float* eW3 = (const float*)d_in[8];
  const float* eb3 = (const float*)d_in[9];
  const float* nW1 = (const float*)d_in[10];
  const float* nb1 = (const float*)d_in[11];
  const float* nW2 = (const float*)d_in[12];
  const float* nb2 = (const float*)d_in[13];
  const float* ng = (const float*)d_in[14];
  const float* nbt = (const float*)d_in[15];
  const float* nW3 = (const float*)d_in[16];
  const float* nb3 = (const float*)d_in[17];

  // ---- workspace
  char* w = (char*)d_ws;
  bf16* eW1f = (bf16*)w;     w += (size_t)131072 * 2;
  bf16* eW2f = (bf16*)w;     w += (size_t)262144 * 2;
  bf16* nW1nf = (bf16*)w;    w += (size_t)65536 * 2;
  bf16* nW2f = (bf16*)w;     w += (size_t)262144 * 2;
  bf16* nW3f = (bf16*)w;     w += (size_t)65536 * 2;
  bf16* Wcf = (bf16*)w;      w += (size_t)262144 * 2;
  bf16* eW3b = (bf16*)w;     w += (size_t)262144 * 2;
  bf16* nW1at = (bf16*)w;    w += (size_t)262144 * 2;
  float* bfold = (float*)w;  w += (size_t)512 * 4;
  bf16* PQ = (bf16*)w;       w += (size_t)8192 * 1024 * 2;
  bf16* S = (bf16*)w;        w += (size_t)8192 * 512 * 2;

  mega_prep<<<dim3(1024, 1, 8), 256, 0, stream>>>(
      eW3, (short*)eW3b, nW1, (unsigned short*)nW1at, eW1, (short*)eW1f, eW2,
      (short*)eW2f, (short*)nW1nf, nW2, (short*)nW2f, nW3, (short*)nW3f);

  combo<<<608, 256, 0, stream>>>(nW1at, eW3b, (short*)Wcf, eb3, nb1, nW1,
                                 bfold, states, eW1f, eb1, PQ);

  edge_ln_seg5<<<2048, 512, 0, stream>>>(PQ, eW2f, eb2, eg, ebt, S);

  node_fused<<<512, 256, 0, stream>>>(states, S, nW1nf, Wcf, nW2f, nW3f,
                                      bfold, action, nW1, nb2, ng, nbt, nb3,
                                      (float*)d_out);

  (void)in_sizes; (void)n_in; (void)out_size; (void)ws_size;
}

// Round 11
// 278.260 us; speedup vs baseline: 1.0246x; 1.0246x over previous
//
#include <hip/hip_runtime.h>
#include <hip/hip_bf16.h>

// TransitionGNN fused pipeline, r11.
// Edge: reverted to r6/r9's proven edge_ln_seg3 (119us; r10 showed barriers
// are NOT its limiter — MfmaUtil pinned at 24% across 3 K-loop structures).
// Tail fix: ALL A-fragment reads were uncoalesced (lane lc <- row m0+lc, 1KB
// stride = 64-way scatter). node_fused + combo now stage A-tiles through LDS
// with coalesced loads; mega_prep frag jobs rebuilt as 32x64 LDS tiles
// (coalesced f32 reads + coalesced 16B frag writes). Numerics bit-identical.

using bf16 = __hip_bfloat16;
typedef __attribute__((ext_vector_type(8))) short bf16x8;
typedef __attribute__((ext_vector_type(4))) short short4v;
typedef __attribute__((ext_vector_type(4))) float f32x4;

#define LDK 40   // LDS row stride (32 + 8 pad) for GEMM staging tiles
#define LDN 520  // 512-col activation tile stride
#define LDT 72   // mega_prep 64-col tile stride (64 + 8 pad)

__device__ __forceinline__ short f2bf(float f) {
  bf16 h = __float2bfloat16(f);
  return *reinterpret_cast<short*>(&h);
}
__device__ __forceinline__ float bs2f(short s) {
  bf16 h = *reinterpret_cast<bf16*>(&s);
  return __bfloat162float(h);
}
__device__ __forceinline__ f32x4 mfma16(bf16x8 a, bf16x8 b, f32x4 c) {
  return __builtin_amdgcn_mfma_f32_16x16x32_bf16(a, b, c, 0, 0, 0);
}
// load 8 consecutive fp32 -> bf16x8 (32B-aligned source)
__device__ __forceinline__ bf16x8 ld8f(const float* p) {
  float4 a = *(const float4*)p;
  float4 b = *(const float4*)(p + 4);
  bf16x8 o;
  o[0] = f2bf(a.x); o[1] = f2bf(a.y); o[2] = f2bf(a.z); o[3] = f2bf(a.w);
  o[4] = f2bf(b.x); o[5] = f2bf(b.y); o[6] = f2bf(b.z); o[7] = f2bf(b.w);
  return o;
}

// ---------------------------------------------------------------- mega_prep
// z=0: eW3 fp32->bf16 cvt [256 blk]; z=1: nW1_agg transpose [256 blk];
// z=2..7: frag-layout swizzles via 32x64 LDS tile (coalesced read+write).
__global__ __launch_bounds__(256) void mega_prep(
    const float* __restrict__ eW3, short* __restrict__ eW3b,
    const float* __restrict__ nW1, unsigned short* __restrict__ nW1at,
    const float* __restrict__ eW1, short* __restrict__ eW1f,
    const float* __restrict__ eW2, short* __restrict__ eW2f,
    short* __restrict__ nW1nf, const float* __restrict__ nW2,
    short* __restrict__ nW2f, const float* __restrict__ nW3,
    short* __restrict__ nW3f) {
  __shared__ unsigned short ttile[32][33];
  __shared__ short ftile[32 * LDT];
  const int z = blockIdx.z, bx = blockIdx.x, t = threadIdx.x;
  if (z == 0) {  // cvt eW3
    if (bx >= 256) return;
    int i = (bx * 256 + t) * 4;
    float4 v = *(const float4*)(eW3 + i);
    short4v o;
    o.x = f2bf(v.x); o.y = f2bf(v.y); o.z = f2bf(v.z); o.w = f2bf(v.w);
    *(short4v*)(eW3b + i) = o;
    return;
  }
  if (z == 1) {  // transpose nW1_agg -> nW1at [n][h]
    if (bx >= 256) return;
    const float* src = nW1 + 132 * 512;
    int bc = (bx & 15) * 32, br = (bx >> 4) * 32;
    int tx = t & 31, ty = t >> 5;
    for (int i = ty; i < 32; i += 8) {
      short s = f2bf(src[(size_t)(br + i) * 512 + bc + tx]);
      ttile[i][tx] = *reinterpret_cast<unsigned short*>(&s);
    }
    __syncthreads();
    for (int i = ty; i < 32; i += 8)
      nW1at[(size_t)(bc + i) * 512 + br + tx] = ttile[tx][i];
    return;
  }
  // frag jobs: block = one kt (32 rows) x 64 src cols (4 gg groups)
  const float* W;
  short* out;
  int ldw, kts, gq, goff, tot_sh;
  switch (z) {
    case 2: W = eW1;           out = eW1f;  ldw = 512; kts = 4;  gq = 8; goff = 0;  tot_sh = 6; break;
    case 3: W = eW1 + 128*512; out = eW1f;  ldw = 512; kts = 4;  gq = 8; goff = 32; tot_sh = 6; break;
    case 4: W = eW2;           out = eW2f;  ldw = 512; kts = 16; gq = 8; goff = 0;  tot_sh = 5; break;
    case 5: W = nW1;           out = nW1nf; ldw = 512; kts = 4;  gq = 8; goff = 0;  tot_sh = 5; break;
    case 6: W = nW2;           out = nW2f;  ldw = 512; kts = 16; gq = 8; goff = 0;  tot_sh = 5; break;
    default: W = nW3;          out = nW3f;  ldw = 128; kts = 16; gq = 2; goff = 0;  tot_sh = 3; break;
  }
  if (bx >= kts * gq) return;
  const int kt = bx / gq, qg = bx % gq;
  {  // coalesced tile load: 32 rows x 64 cols f32 -> bf16 LDS
    int r = t >> 3, c0 = (t & 7) * 8;
    const float* src = W + (size_t)(kt * 32 + r) * ldw + qg * 64 + c0;
    *(bf16x8*)&ftile[r * LDT + c0] = ld8f(src);
  }
  __syncthreads();
  {  // coalesced frag write: og in 0..3, lane 0..63 -> 16B per lane
    int og = t >> 6, lane = t & 63, q = lane >> 4, lc = lane & 15;
    int gg = qg * 4 + og;
    size_t base = ((size_t)((kt << tot_sh) + gg + goff)) << 9;
    bf16x8 v;
#pragma unroll
    for (int j = 0; j < 8; ++j) v[j] = ftile[(q * 8 + j) * LDT + og * 16 + lc];
    *(bf16x8*)(out + base + lane * 8) = v;
  }
}

// ---------------------------------------------------------------- combo
// blocks 0..63: Wc frag tiles; 64..95: bias fold (32-way); 96..607: PQ gemm
// (states A-tile now staged through LDS — was a 64-way scattered read).
__global__ __launch_bounds__(256) void combo(
    const bf16* __restrict__ nW1at, const bf16* __restrict__ eW3b,
    short* __restrict__ Wcf, const float* __restrict__ eb3,
    const float* __restrict__ nb1, const float* __restrict__ nW1,
    float* __restrict__ bfold, const float* __restrict__ states,
    const bf16* __restrict__ eW1f, const float* __restrict__ eb1,
    bf16* __restrict__ PQ) {
  __shared__ short Al[64 * LDK];
  __shared__ short Bl[64 * LDK];
  __shared__ float red[256];
  __shared__ short sts[16 * 136];
  const int bid = blockIdx.x;
  const int t = threadIdx.x;
  const int wid = t >> 6, lane = t & 63, q = lane >> 4, lc = lane & 15;
  const f32x4 zz = {0.f, 0.f, 0.f, 0.f};

  if (bid < 64) {  // ---- Wc tile (64x64), K=512
    const int wm = wid >> 1, wn = wid & 1;
    const int n0 = (bid >> 3) * 64, k0 = (bid & 7) * 64;
    f32x4 acc[2][2];
#pragma unroll
    for (int mb = 0; mb < 2; ++mb)
#pragma unroll
      for (int nb = 0; nb < 2; ++nb) acc[mb][nb] = zz;
    const int sr = t >> 2, seg = t & 3;
    for (int h0 = 0; h0 < 512; h0 += 32) {
      *(uint4*)&Al[sr * LDK + seg * 8] =
          *(const uint4*)(nW1at + (size_t)(n0 + sr) * 512 + h0 + seg * 8);
      *(uint4*)&Bl[sr * LDK + seg * 8] =
          *(const uint4*)(eW3b + (size_t)(k0 + sr) * 512 + h0 + seg * 8);
      __syncthreads();
      bf16x8 af[2], bfr[2];
#pragma unroll
      for (int mb = 0; mb < 2; ++mb)
        af[mb] = *(const bf16x8*)&Al[(wm * 32 + mb * 16 + lc) * LDK + q * 8];
#pragma unroll
      for (int nb = 0; nb < 2; ++nb)
        bfr[nb] = *(const bf16x8*)&Bl[(wn * 32 + nb * 16 + lc) * LDK + q * 8];
#pragma unroll
      for (int mb = 0; mb < 2; ++mb)
#pragma unroll
        for (int nb = 0; nb < 2; ++nb)
          acc[mb][nb] = mfma16(af[mb], bfr[nb], acc[mb][nb]);
      __syncthreads();
    }
#pragma unroll
    for (int mb = 0; mb < 2; ++mb)
#pragma unroll
      for (int nb = 0; nb < 2; ++nb)
#pragma unroll
        for (int r = 0; r < 4; ++r) {
          int n = n0 + wm * 32 + mb * 16 + q * 4 + r;
          int k = k0 + wn * 32 + nb * 16 + lc;
          int kt = k >> 5, kin = k & 31, qf = kin >> 3, jf = kin & 7;
          Wcf[(((size_t)kt * 32 + (n >> 4)) * 64 + qf * 16 + (n & 15)) * 8 +
              jf] = f2bf(acc[mb][nb][r]);
        }
    return;
  }
  if (bid < 96) {  // ---- bias fold, 32-way parallel
    const int n = (bid - 64) * 16 + (t & 15);
    const int sl = t >> 4;
    float s = 0.f;
#pragma unroll 8
    for (int h = sl * 32; h < sl * 32 + 32; ++h)
      s += eb3[h] * nW1[(size_t)(132 + h) * 512 + n];
    red[sl * 16 + (t & 15)] = s;
    __syncthreads();
    if (t < 16) {
      float tot = 0.f;
#pragma unroll
      for (int k = 0; k < 16; ++k) tot += red[k * 16 + t];
      bfold[(bid - 64) * 16 + t] = nb1[(bid - 64) * 16 + t] + 15.f * tot;
    }
    return;
  }
  // ---- PQ gemm: 16-row tile, K=128, N=1024; states staged via LDS
  const int m0 = (bid - 96) * 16;
  {
    int r = t >> 4, c8 = (t & 15) * 8;
    *(bf16x8*)&sts[r * 136 + c8] =
        ld8f(states + (size_t)(m0 + r) * 128 + c8);
  }
  __syncthreads();
  f32x4 acc[16];
#pragma unroll
  for (int nb = 0; nb < 16; ++nb) acc[nb] = zz;
#pragma unroll
  for (int kt = 0; kt < 4; ++kt) {
    bf16x8 af = *(const bf16x8*)&sts[lc * 136 + kt * 32 + q * 8];
#pragma unroll
    for (int nb = 0; nb < 16; ++nb) {
      bf16x8 bfr = *(const bf16x8*)(eW1f +
                                    (((size_t)kt * 64 + wid * 16 + nb) * 64 +
                                     lane) * 8);
      acc[nb] = mfma16(af, bfr, acc[nb]);
    }
  }
#pragma unroll
  for (int nb = 0; nb < 16; ++nb) {
    int col = wid * 256 + nb * 16 + lc;
    float bv = (col < 512) ? eb1[col] : 0.f;
#pragma unroll
    for (int r = 0; r < 4; ++r)
      PQ[(size_t)(m0 + q * 4 + r) * 1024 + col] =
          __float2bfloat16(acc[nb][r] + bv);
  }
}

// ---------------------------------------------------------------- edge kernel
// r6/r9's proven edge_ln_seg3 (byte-identical): A-tile double-buffered LDS,
// B-frags direct global from eW2f, launch_bounds(512,4) -> 2 blocks/CU.
__global__ __launch_bounds__(512, 4) void edge_ln_seg3(
    const bf16* __restrict__ PQ, const bf16* __restrict__ Wf,
    const float* __restrict__ b2, const float* __restrict__ g,
    const float* __restrict__ be, bf16* __restrict__ S) {
  __shared__ short Alds[2][64 * LDK];
  __shared__ float s_sum[64 * 8];
  __shared__ float s_sq[64 * 8];
  const int t = threadIdx.x;
  const int w = t >> 6, lane = t & 63, q = lane >> 4, lc = lane & 15;
  const int g0 = blockIdx.x * 4;
  const int bb = g0 >> 4;
  const f32x4 zz = {0.f, 0.f, 0.f, 0.f};
  f32x4 acc[4][4];
#pragma unroll
  for (int mb = 0; mb < 4; ++mb)
#pragma unroll
    for (int nb = 0; nb < 4; ++nb) acc[mb][nb] = zz;

  const int ar = t >> 3;
  const int kk = (t & 7) * 4;
  const int gA = ar >> 4;
  const int slot = ar & 15;
  const int aiA = (g0 & 15) + gA;
  const bool padA = (slot == 15);
  const int dstA = padA ? 0 : slot + (slot >= aiA ? 1 : 0);
  const bf16* pA = PQ + (size_t)(g0 + gA) * 1024 + kk;
  const bf16* qA = PQ + (size_t)(bb * 16 + dstA) * 1024 + 512 + kk;

  auto buildA = [&](int kt, int buf) {
    short4v av = {0, 0, 0, 0};
    if (!padA) {
      short4v pv = *(const short4v*)(pA + kt * 32);
      short4v qv = *(const short4v*)(qA + kt * 32);
      av.x = f2bf(fmaxf(bs2f(pv.x) + bs2f(qv.x), 0.f));
      av.y = f2bf(fmaxf(bs2f(pv.y) + bs2f(qv.y), 0.f));
      av.z = f2bf(fmaxf(bs2f(pv.z) + bs2f(qv.z), 0.f));
      av.w = f2bf(fmaxf(bs2f(pv.w) + bs2f(qv.w), 0.f));
    }
    *(short4v*)&Alds[buf][ar * LDK + kk] = av;
  };

  buildA(0, 0);
#pragma unroll 1
  for (int kt = 0; kt < 16; ++kt) {
    __syncthreads();
    const int cur = kt & 1;
    bf16x8 bfr[4], af[4];
#pragma unroll
    for (int nb = 0; nb < 4; ++nb)
      bfr[nb] = *(const bf16x8*)(Wf +
                                 (((size_t)kt * 32 + w * 4 + nb) * 64 + lane) * 8);
#pragma unroll
    for (int mb = 0; mb < 4; ++mb)
      af[mb] = *(const bf16x8*)&Alds[cur][(mb * 16 + lc) * LDK + q * 8];
    if (kt < 15) buildA(kt + 1, cur ^ 1);
#pragma unroll
    for (int mb = 0; mb < 4; ++mb)
#pragma unroll
      for (int nb = 0; nb < 4; ++nb)
        acc[mb][nb] = mfma16(af[mb], bfr[nb], acc[mb][nb]);
  }

  float bv[4], gv[4], bev[4];
#pragma unroll
  for (int nb = 0; nb < 4; ++nb) {
    int col = w * 64 + nb * 16 + lc;
    bv[nb] = b2[col];
    gv[nb] = g[col];
    bev[nb] = be[col];
  }
#pragma unroll
  for (int mb = 0; mb < 4; ++mb)
#pragma unroll
    for (int nb = 0; nb < 4; ++nb)
#pragma unroll
      for (int r = 0; r < 4; ++r) acc[mb][nb][r] += bv[nb];

#pragma unroll
  for (int mb = 0; mb < 4; ++mb) {
    float ps[4] = {0, 0, 0, 0}, pq2[4] = {0, 0, 0, 0};
#pragma unroll
    for (int nb = 0; nb < 4; ++nb)
#pragma unroll
      for (int r = 0; r < 4; ++r) {
        float x = acc[mb][nb][r];
        ps[r] += x;
        pq2[r] += x * x;
      }
#pragma unroll
    for (int d = 1; d < 16; d <<= 1)
#pragma unroll
      for (int r = 0; r < 4; ++r) {
        ps[r] += __shfl_xor(ps[r], d, 64);
        pq2[r] += __shfl_xor(pq2[r], d, 64);
      }
    if (lc == 0)
#pragma unroll
      for (int r = 0; r < 4; ++r) {
        int row = mb * 16 + q * 4 + r;
        s_sum[row * 8 + w] = ps[r];
        s_sq[row * 8 + w] = pq2[r];
      }
  }
  __syncthreads();
#pragma unroll
  for (int mb = 0; mb < 4; ++mb) {
    float sv[4] = {0, 0, 0, 0};
#pragma unroll
    for (int r = 0; r < 4; ++r) {
      int row = mb * 16 + q * 4 + r;
      float tot = 0.f, tsq = 0.f;
#pragma unroll
      for (int wv = 0; wv < 8; ++wv) {
        tot += s_sum[row * 8 + wv];
        tsq += s_sq[row * 8 + wv];
      }
      float m = tot * (1.f / 512.f);
      float rstd = rsqrtf(tsq * (1.f / 512.f) - m * m + 1e-5f);
#pragma unroll
      for (int nb = 0; nb < 4; ++nb) {
        float h = (acc[mb][nb][r] - m) * rstd * gv[nb] + bev[nb];
        h = fmaxf(h, 0.f);
        if (q * 4 + r != 15) sv[nb] += h;
      }
    }
#pragma unroll
    for (int nb = 0; nb < 4; ++nb) {
      sv[nb] += __shfl_xor(sv[nb], 16, 64);
      sv[nb] += __shfl_xor(sv[nb], 32, 64);
    }
    if (lane < 16)
#pragma unroll
      for (int nb = 0; nb < 4; ++nb)
        S[(size_t)(g0 + mb) * 512 + w * 64 + nb * 16 + lc] =
            __float2bfloat16(sv[nb]);
  }
}

// ---------------------------------------------------------------- node_fused
// A-tiles (states 16x128 f32, S 16x512 bf16) staged via coalesced LDS loads;
// phases A (n1), B (LN), C (out) read A-frags from LDS only.
__global__ __launch_bounds__(256) void node_fused(
    const float* __restrict__ states, const bf16* __restrict__ S,
    const bf16* __restrict__ nW1nf, const bf16* __restrict__ Wcf,
    const bf16* __restrict__ nW2f, const bf16* __restrict__ nW3f,
    const float* __restrict__ bfold, const int* __restrict__ action,
    const float* __restrict__ nW1, const float* __restrict__ nb2,
    const float* __restrict__ ng, const float* __restrict__ nbt,
    const float* __restrict__ nb3, float* __restrict__ Out) {
  __shared__ short sts[16 * 136];
  __shared__ short Ss[16 * LDN];
  __shared__ short n1s[16 * LDN];
  __shared__ float s_sum[16 * 4];
  __shared__ float s_sq[16 * 4];
  const int t = threadIdx.x;
  const int wid = t >> 6, lane = t & 63, q = lane >> 4, lc = lane & 15;
  const int m0 = blockIdx.x * 16;
  const f32x4 zz = {0.f, 0.f, 0.f, 0.f};

  // ---- stage A-tiles (coalesced)
  {
    int r = t >> 4, c8 = (t & 15) * 8;
    *(bf16x8*)&sts[r * 136 + c8] =
        ld8f(states + (size_t)(m0 + r) * 128 + c8);
    int sgi = t & 15;
#pragma unroll
    for (int it = 0; it < 4; ++it) {
      int seg = sgi + it * 16;
      *(uint4*)&Ss[r * LDN + seg * 8] =
          *(const uint4*)(S + (size_t)(m0 + r) * 512 + seg * 8);
    }
  }
  __syncthreads();

  // ---- phase A: n1
  f32x4 acc[8];
#pragma unroll
  for (int nb = 0; nb < 8; ++nb) acc[nb] = zz;
#pragma unroll
  for (int kt = 0; kt < 4; ++kt) {
    bf16x8 af = *(const bf16x8*)&sts[lc * 136 + kt * 32 + q * 8];
#pragma unroll
    for (int nb = 0; nb < 8; ++nb) {
      bf16x8 bfr = *(const bf16x8*)(nW1nf +
                                    (((size_t)kt * 32 + wid * 8 + nb) * 64 +
                                     lane) * 8);
      acc[nb] = mfma16(af, bfr, acc[nb]);
    }
  }
#pragma unroll 2
  for (int kt = 0; kt < 16; ++kt) {
    bf16x8 af = *(const bf16x8*)&Ss[lc * LDN + kt * 32 + q * 8];
#pragma unroll
    for (int nb = 0; nb < 8; ++nb) {
      bf16x8 bfr = *(const bf16x8*)(Wcf +
                                    (((size_t)kt * 32 + wid * 8 + nb) * 64 +
                                     lane) * 8);
      acc[nb] = mfma16(af, bfr, acc[nb]);
    }
  }
  {
    int a = action[m0 >> 4];
    int aw = a >> 2, ac4 = a & 3;
#pragma unroll
    for (int nb = 0; nb < 8; ++nb) {
      int col = wid * 128 + nb * 16 + lc;
      float bv = bfold[col];
      float awv = nW1[(size_t)(128 + ac4) * 512 + col];
#pragma unroll
      for (int r = 0; r < 4; ++r) {
        int row = q * 4 + r;
        float x = acc[nb][r] + bv + (row == aw ? awv : 0.f);
        n1s[row * LDN + col] = f2bf(fmaxf(x, 0.f));
      }
    }
  }
  __syncthreads();

  // ---- phase B: n2 = relu(LN(n1@nW2 + nb2))
  f32x4 acc2[8];
#pragma unroll
  for (int nb = 0; nb < 8; ++nb) acc2[nb] = zz;
#pragma unroll 2
  for (int kt = 0; kt < 16; ++kt) {
    bf16x8 af = *(const bf16x8*)&n1s[lc * LDN + kt * 32 + q * 8];
#pragma unroll
    for (int nb = 0; nb < 8; ++nb) {
      bf16x8 bfr = *(const bf16x8*)(nW2f +
                                    (((size_t)kt * 32 + wid * 8 + nb) * 64 +
                                     lane) * 8);
      acc2[nb] = mfma16(af, bfr, acc2[nb]);
    }
  }
  float gv[8], bev[8];
  {
    float ps[4] = {0, 0, 0, 0}, pq2[4] = {0, 0, 0, 0};
#pragma unroll
    for (int nb = 0; nb < 8; ++nb) {
      int col = wid * 128 + nb * 16 + lc;
      float bv = nb2[col];
      gv[nb] = ng[col];
      bev[nb] = nbt[col];
#pragma unroll
      for (int r = 0; r < 4; ++r) {
        acc2[nb][r] += bv;
        ps[r] += acc2[nb][r];
        pq2[r] += acc2[nb][r] * acc2[nb][r];
      }
    }
#pragma unroll
    for (int d = 1; d < 16; d <<= 1)
#pragma unroll
      for (int r = 0; r < 4; ++r) {
        ps[r] += __shfl_xor(ps[r], d, 64);
        pq2[r] += __shfl_xor(pq2[r], d, 64);
      }
    if (lc == 0)
#pragma unroll
      for (int r = 0; r < 4; ++r) {
        s_sum[(q * 4 + r) * 4 + wid] = ps[r];
        s_sq[(q * 4 + r) * 4 + wid] = pq2[r];
      }
  }
  __syncthreads();
#pragma unroll
  for (int r = 0; r < 4; ++r) {
    int row = q * 4 + r;
    float tot = 0.f, tsq = 0.f;
#pragma unroll
    for (int wv = 0; wv < 4; ++wv) {
      tot += s_sum[row * 4 + wv];
      tsq += s_sq[row * 4 + wv];
    }
    float m = tot * (1.f / 512.f);
    float rstd = rsqrtf(tsq * (1.f / 512.f) - m * m + 1e-5f);
#pragma unroll
    for (int nb = 0; nb < 8; ++nb) {
      int col = wid * 128 + nb * 16 + lc;
      float h = (acc2[nb][r] - m) * rstd * gv[nb] + bev[nb];
      n1s[row * LDN + col] = f2bf(fmaxf(h, 0.f));
    }
  }
  __syncthreads();

  // ---- phase C: out = n2@nW3 + nb3
  f32x4 acc3[2];
#pragma unroll
  for (int nb = 0; nb < 2; ++nb) acc3[nb] = zz;
#pragma unroll 2
  for (int kt = 0; kt < 16; ++kt) {
    bf16x8 af = *(const bf16x8*)&n1s[lc * LDN + kt * 32 + q * 8];
#pragma unroll
    for (int nb = 0; nb < 2; ++nb) {
      bf16x8 bfr = *(const bf16x8*)(nW3f +
                                    (((size_t)kt * 8 + wid * 2 + nb) * 64 +
                                     lane) * 8);
      acc3[nb] = mfma16(af, bfr, acc3[nb]);
    }
  }
#pragma unroll
  for (int nb = 0; nb < 2; ++nb) {
    int col = wid * 32 + nb * 16 + lc;
    float b3 = nb3[col];
#pragma unroll
    for (int r = 0; r < 4; ++r)
      Out[(size_t)(m0 + q * 4 + r) * 128 + col] = acc3[nb][r] + b3;
  }
}

// ---------------------------------------------------------------- launch
extern "C" void kernel_launch(void* const* d_in, const int* in_sizes, int n_in,
                              void* d_out, int out_size, void* d_ws,
                              size_t ws_size, hipStream_t stream) {
  const float* states = (const float*)d_in[0];
  const int* action = (const int*)d_in[1];
  const float* eW1 = (const float*)d_in[2];
  const float* eb1 = (const float*)d_in[3];
  const float* eW2 = (const float*)d_in[4];
  const float* eb2 = (const float*)d_in[5];
  const float* eg = (const float*)d_in[6];
  const float* ebt = (const float*)d_in[7];
  const float* eW3 = (const float*)d_in[8];
  const float* eb3 = (const float*)d_in[9];
  const float* nW1 = (const float*)d_in[10];
  const float* nb1 = (const float*)d_in[11];
  const float* nW2 = (const float*)d_in[12];
  const float* nb2 = (const float*)d_in[13];
  const float* ng = (const float*)d_in[14];
  const float* nbt = (const float*)d_in[15];
  const float* nW3 = (const float*)d_in[16];
  const float* nb3 = (const float*)d_in[17];

  // ---- workspace
  char* w = (char*)d_ws;
  bf16* eW1f = (bf16*)w;     w += (size_t)131072 * 2;
  bf16* eW2f = (bf16*)w;     w += (size_t)262144 * 2;
  bf16* nW1nf = (bf16*)w;    w += (size_t)65536 * 2;
  bf16* nW2f = (bf16*)w;     w += (size_t)262144 * 2;
  bf16* nW3f = (bf16*)w;     w += (size_t)65536 * 2;
  bf16* Wcf = (bf16*)w;      w += (size_t)262144 * 2;
  bf16* eW3b = (bf16*)w;     w += (size_t)262144 * 2;
  bf16* nW1at = (bf16*)w;    w += (size_t)262144 * 2;
  float* bfold = (float*)w;  w += (size_t)512 * 4;
  bf16* PQ = (bf16*)w;       w += (size_t)8192 * 1024 * 2;
  bf16* S = (bf16*)w;        w += (size_t)8192 * 512 * 2;

  mega_prep<<<dim3(256, 1, 8), 256, 0, stream>>>(
      eW3, (short*)eW3b, nW1, (unsigned short*)nW1at, eW1, (short*)eW1f, eW2,
      (short*)eW2f, (short*)nW1nf, nW2, (short*)nW2f, nW3, (short*)nW3f);

  combo<<<608, 256, 0, stream>>>(nW1at, eW3b, (short*)Wcf, eb3, nb1, nW1,
                                 bfold, states, eW1f, eb1, PQ);

  edge_ln_seg3<<<2048, 512, 0, stream>>>(PQ, eW2f, eb2, eg, ebt, S);

  node_fused<<<512, 256, 0, stream>>>(states, S, nW1nf, Wcf, nW2f, nW3f,
                                      bfold, action, nW1, nb2, ng, nbt, nb3,
                                      (float*)d_out);

  (void)in_sizes; (void)n_in; (void)out_size; (void)ws_size;
}